// Round 1
// baseline (448.321 us; speedup 1.0000x reference)
//
#include <hip/hip_runtime.h>
#include <hip/hip_bf16.h>

// GFNO 3D p4-equivariant conv via implicit GEMM on bf16 MFMA. R4:
//  - K-loop restructured: B-slab (6 h-rows x 64 w x 64 ic = 48KB) staged to LDS
//    ONCE per ky (3 stage phases/block instead of 54) -> barriers 108 -> 6.
//    The 18 (kx,kt,ich) K-steps per ky run barrier-free out of LDS, with kx as
//    a row offset and kt as a w-column offset at ds_read time.
//  - LDS XOR swizzle (ic_byte ^= (wcol&7)<<4) kills the 16-way ds_read_b128
//    bank conflict of the 128B-stride layout; inverse swizzle is applied to the
//    per-lane GLOBAL source address so global_load_lds's linear write lands
//    pre-swizzled (guide rule 21).
//  - A operand: direct per-lane global_load_dwordx4 from L2-resident wT with
//    1-step software prefetch (no cross-wave sync needed).
//  - staged rows clamped to h<=63 (clamped rows feed only discarded outputs)
//    -> no OOB reads past xT.
//  - bijective XCD swizzle of blockIdx (1920 % 8 == 0) for L2 halo reuse.
//  - s_setprio(1) around MFMA cluster (cross-block stage/compute diversity).
//
// GEMM view: M=64 (oc), N=4*30*62*62 spatial, K=27 taps x 64 ic.
// ws layout:
//   [0, 221184)            wT  bf16 [27 tap][64 oc][64 ic]
//   [262144, +67108864)    xT  bf16 [4 nb][32 d][64 h][64 w][64 ic]

typedef __attribute__((ext_vector_type(8))) short bf16x8;
typedef __attribute__((ext_vector_type(4))) float f32x4;

__device__ __forceinline__ void gl_lds16(const void* g, void* l) {
    __builtin_amdgcn_global_load_lds(
        (const __attribute__((address_space(1))) unsigned int*)g,
        (__attribute__((address_space(3))) unsigned int*)l, 16, 0, 0);
}

// ---- symmetrized weights -> wT[tap][oc][ic] (bf16) ----------------------
__global__ __launch_bounds__(256) void build_wT(const float* __restrict__ W,
                                                __hip_bfloat16* __restrict__ wT) {
    int idx = blockIdx.x * 256 + threadIdx.x;   // (tap*64 + oc)*64 + ic
    if (idx >= 27 * 64 * 64) return;
    int ic = idx & 63;
    int oc = (idx >> 6) & 63;
    int tap = idx >> 12;
    int kt = tap % 3, kx = (tap / 3) % 3, ky = tap / 9;
    int o = oc >> 2, kc = oc & 3, i = ic >> 2, gs = ic & 3;
    int sy = ky, sx = kx;
    for (int t = 0; t < kc; ++t) {              // ws[k][g,y,x] = ws[k-1][(g-1)%4, x, 2-y]
        int ny = sx, nx = 2 - sy;
        sy = ny; sx = nx;
        gs = (gs + 3) & 3;
    }
    wT[idx] = __float2bfloat16(W[((o * 16 + i) * 4 + gs) * 27 + sy * 9 + sx * 3 + kt]);
}

// ---- x (NCDHW fp32) -> xT[nb][d][h][w][ic] (bf16) -----------------------
__device__ __forceinline__ unsigned int pack2(float a, float b) {
    union { __hip_bfloat162 h2; unsigned int u; } c;
    c.h2 = __hip_bfloat162{__float2bfloat16(a), __float2bfloat16(b)};
    return c.u;
}

__global__ __launch_bounds__(256) void transpose_x(const float* __restrict__ x,
                                                   __hip_bfloat16* __restrict__ xT) {
    __shared__ unsigned int ls[64 * 37];   // [w][ic/2] bf16x2, stride 37 (conflict-free)
    int bid = blockIdx.x;                  // (nb*32 + d)*8 + hq
    int hq = bid & 7, d = (bid >> 3) & 31, nb = bid >> 8;
    int tid = threadIdx.x;
    int w4 = tid & 15;                     // float4 index along w
    int kp = tid >> 4;                     // 0..15

    for (int hi = 0; hi < 8; ++hi) {
        int h = hq * 8 + hi;
        float4 v0[2], v1[2];
#pragma unroll
        for (int r = 0; r < 2; ++r) {
            int p = r * 16 + kp;           // ic pair index 0..31
            const float* src = x + ((((size_t)nb * 64 + 2 * p) * 32 + d) * 64 + h) * 64 + w4 * 4;
            v0[r] = *(const float4*)(src);
            v1[r] = *(const float4*)(src + 32 * 64 * 64);   // ic+1 plane
        }
        __syncthreads();   // prior iteration's reads complete
#pragma unroll
        for (int r = 0; r < 2; ++r) {
            int p = r * 16 + kp;
            ls[(w4 * 4 + 0) * 37 + p] = pack2(v0[r].x, v1[r].x);
            ls[(w4 * 4 + 1) * 37 + p] = pack2(v0[r].y, v1[r].y);
            ls[(w4 * 4 + 2) * 37 + p] = pack2(v0[r].z, v1[r].z);
            ls[(w4 * 4 + 3) * 37 + p] = pack2(v0[r].w, v1[r].w);
        }
        __syncthreads();
        __hip_bfloat16* obase = xT + (((size_t)nb * 32 + d) * 64 + h) * 4096;
#pragma unroll
        for (int c = tid; c < 512; c += 256) {
            int ww = c >> 3, icc = c & 7;
            const unsigned int* q = ls + ww * 37 + icc * 4;
            uint4 v;
            v.x = q[0]; v.y = q[1]; v.z = q[2]; v.w = q[3];
            *(uint4*)(obase + ww * 64 + icc * 8) = v;
        }
    }
}

// ---- implicit GEMM conv -------------------------------------------------
// block: 64 oc x 256 spatial (4 h-rows x 64 w), wave w owns h-row w.
// per ky: stage sB[row 0..5][wcol 0..63][ic 0..63] (XOR-swizzled), then
// 18 barrier-free K-steps (kx,kt,ich). A frags loaded direct from global wT.
__global__ __launch_bounds__(256, 3) void conv_mfma(const __hip_bfloat16* __restrict__ xT,
                                                    const __hip_bfloat16* __restrict__ wT,
                                                    const float* __restrict__ Bp,
                                                    float* __restrict__ out) {
    // [6][64][64] bf16 + 128-short slack (kt shift can read 2 cols past row 5)
    __shared__ __align__(16) short sB[6 * 4096 + 128];   // 49,408 B -> 3 blocks/CU

    int orig = blockIdx.x;                     // 1920 blocks, 1920 % 8 == 0
    int bid = (orig & 7) * 240 + (orig >> 3);  // bijective XCD swizzle
    int ht = bid % 16;                 // h-tile of 4 rows
    int d  = (bid / 16) % 30;
    int nb = bid / 480;
    int h0 = ht * 4;

    int tid = threadIdx.x;
    int w = tid >> 6;                  // wave id = h-row
    int lane = tid & 63;
    int quad = lane >> 4, col = lane & 15;

    f32x4 acc[4][4];
#pragma unroll
    for (int mt = 0; mt < 4; ++mt)
#pragma unroll
        for (int nt = 0; nt < 4; ++nt) acc[mt][nt] = (f32x4)(0.0f);

    // staging: per-lane pre-swizzled source offset (shorts).
    // LDS[wcol*64 + j16*8 + t] = xrow[wcol*64 + (j16 ^ (wcol&7))*8 + t]
    int srcl = ((lane >> 3) << 6) + (((lane & 7) ^ (lane >> 3)) << 3);

    // A fragment: lane reads wT[tap][oc = mt*16+col][ich*32 + quad*8 ..+8]
    int aoff = col * 64 + quad * 8;
    const __hip_bfloat16* aP = wT + aoff;      // advances 9*4096 per ky
    bf16x8 afc[4];
#pragma unroll
    for (int mt = 0; mt < 4; ++mt) afc[mt] = *(const bf16x8*)(aP + mt * 1024);

    const __hip_bfloat16* xb = xT + (size_t)nb * 8388608 + (size_t)d * 262144;

    for (int ky = 0; ky < 3; ++ky) {
        __syncthreads();   // previous ky's ds_reads complete before overwrite
        // stage 48KB: 48 segs of 1KB; wave w takes segs w, w+4, ...
#pragma unroll
        for (int i = 0; i < 12; ++i) {
            int p = w + i * 4;                 // seg: row = p>>3, j = p&7
            int hh = h0 + (p >> 3);
            if (hh > 63) hh = 63;              // clamped rows feed only discarded outputs
            gl_lds16(xb + (size_t)ky * 262144 + hh * 4096 + (p & 7) * 512 + srcl,
                     (char*)sB + p * 1024);
        }
        __syncthreads();   // staging landed (vmcnt(0) drain, once per ky)

#pragma unroll
        for (int s = 0; s < 18; ++s) {
            const int taps = s >> 1, ich = s & 1;
            const int kt = taps % 3, kx = taps / 3;

            // prefetch next step's A frags (L2-resident wT)
            const __hip_bfloat16* an = (s < 17)
                ? aP + (((s + 1) >> 1) * 4096 + ((s + 1) & 1) * 32)
                : aP + 9 * 4096;               // next ky's tap0 (ky=2: reads ws gap, harmless)
            bf16x8 afn[4];
#pragma unroll
            for (int mt = 0; mt < 4; ++mt) afn[mt] = *(const bf16x8*)(an + mt * 1024);

            // B frags from LDS: row = w+kx, wcol = nt*16 + col + kt (2-way max conflict)
            int wc = col + kt;
            const short* pb = sB + ((w + kx) * 64 + wc) * 64
                              + ((ich * 32 + quad * 8) ^ ((wc & 7) << 3));
            bf16x8 bfr[4];
#pragma unroll
            for (int nt = 0; nt < 4; ++nt) bfr[nt] = *(const bf16x8*)(pb + nt * 1024);

            __builtin_amdgcn_s_setprio(1);
#pragma unroll
            for (int mt = 0; mt < 4; ++mt)
#pragma unroll
                for (int nt = 0; nt < 4; ++nt)
                    acc[mt][nt] = __builtin_amdgcn_mfma_f32_16x16x32_bf16(
                        afc[mt], bfr[nt], acc[mt][nt], 0, 0, 0);
            __builtin_amdgcn_s_setprio(0);

#pragma unroll
            for (int mt = 0; mt < 4; ++mt) afc[mt] = afn[mt];
        }
        aP += 9 * 4096;
    }

    // epilogue: D row = quad*4 + r (oc), col = n
    int hrow = h0 + w;
    if (hrow < 62) {
#pragma unroll
        for (int mt = 0; mt < 4; ++mt) {
            float bias = Bp[mt * 4 + quad];
#pragma unroll
            for (int nt = 0; nt < 4; ++nt) {
                int wp = nt * 16 + col;
                if (wp < 62) {
#pragma unroll
                    for (int r = 0; r < 4; ++r) {
                        int oc = mt * 16 + quad * 4 + r;
                        out[(((size_t)nb * 64 + oc) * 30 + d) * 3844 + hrow * 62 + wp]
                            = acc[mt][nt][r] + bias;
                    }
                }
            }
        }
    }
}

extern "C" void kernel_launch(void* const* d_in, const int* in_sizes, int n_in,
                              void* d_out, int out_size, void* d_ws, size_t ws_size,
                              hipStream_t stream) {
    const float* x = (const float*)d_in[0];
    const float* W = (const float*)d_in[1];
    const float* Bp = (const float*)d_in[2];
    float* out = (float*)d_out;

    char* ws = (char*)d_ws;
    __hip_bfloat16* wT = (__hip_bfloat16*)ws;              // 221,184 B
    __hip_bfloat16* xT = (__hip_bfloat16*)(ws + 262144);   // 67,108,864 B

    build_wT<<<(27 * 64 * 64 + 255) / 256, 256, 0, stream>>>(W, wT);
    transpose_x<<<4 * 32 * 8, 256, 0, stream>>>(x, xT);
    conv_mfma<<<4 * 30 * 16, 256, 0, stream>>>(xT, wT, Bp, out);
}

// Round 2
// 338.032 us; speedup vs baseline: 1.3263x; 1.3263x over previous
//
#include <hip/hip_runtime.h>
#include <hip/hip_bf16.h>

// GFNO 3D p4-equivariant conv via implicit GEMM on bf16 MFMA. R5:
//  - B path (kept from R4): 48KB 6-row slab staged to LDS once per ky,
//    XOR-swizzled both sides (bank conflicts measured 0), XCD-swizzled grid
//    (FETCH 274MB -> 43MB).
//  - A path (fixed): R4's per-lane global A-loads were latency-bound (compiler
//    folded the 1-deep prefetch under register pressure; VGPR=84 < acc+frags).
//    A now streams global->LDS through a per-tap 8KB double buffer: issue
//    stage of A[tap+1] at top of tap, compute both ich halves from A[tap],
//    one __syncthreads() per tap (vmcnt drain covers only 2 just-issued loads).
//    A LDS layout uses the same XOR involution (pre-swizzled global source).
//  - 30 barriers/block (vs 108 in R3 / 6 in R4), all cheap.
//
// GEMM view: M=64 (oc), N=4*30*62*62 spatial, K=27 taps x 64 ic.
// ws layout:
//   [0, 221184)            wT  bf16 [27 tap][64 oc][64 ic]
//   [221184, 262144)       gap (tap-27 A-prefetch overrun reads this; unused)
//   [262144, +67108864)    xT  bf16 [4 nb][32 d][64 h][64 w][64 ic]

typedef __attribute__((ext_vector_type(8))) short bf16x8;
typedef __attribute__((ext_vector_type(4))) float f32x4;

__device__ __forceinline__ void gl_lds16(const void* g, void* l) {
    __builtin_amdgcn_global_load_lds(
        (const __attribute__((address_space(1))) unsigned int*)g,
        (__attribute__((address_space(3))) unsigned int*)l, 16, 0, 0);
}

// ---- symmetrized weights -> wT[tap][oc][ic] (bf16) ----------------------
__global__ __launch_bounds__(256) void build_wT(const float* __restrict__ W,
                                                __hip_bfloat16* __restrict__ wT) {
    int idx = blockIdx.x * 256 + threadIdx.x;   // (tap*64 + oc)*64 + ic
    if (idx >= 27 * 64 * 64) return;
    int ic = idx & 63;
    int oc = (idx >> 6) & 63;
    int tap = idx >> 12;
    int kt = tap % 3, kx = (tap / 3) % 3, ky = tap / 9;
    int o = oc >> 2, kc = oc & 3, i = ic >> 2, gs = ic & 3;
    int sy = ky, sx = kx;
    for (int t = 0; t < kc; ++t) {              // ws[k][g,y,x] = ws[k-1][(g-1)%4, x, 2-y]
        int ny = sx, nx = 2 - sy;
        sy = ny; sx = nx;
        gs = (gs + 3) & 3;
    }
    wT[idx] = __float2bfloat16(W[((o * 16 + i) * 4 + gs) * 27 + sy * 9 + sx * 3 + kt]);
}

// ---- x (NCDHW fp32) -> xT[nb][d][h][w][ic] (bf16) -----------------------
__device__ __forceinline__ unsigned int pack2(float a, float b) {
    union { __hip_bfloat162 h2; unsigned int u; } c;
    c.h2 = __hip_bfloat162{__float2bfloat16(a), __float2bfloat16(b)};
    return c.u;
}

__global__ __launch_bounds__(256) void transpose_x(const float* __restrict__ x,
                                                   __hip_bfloat16* __restrict__ xT) {
    __shared__ unsigned int ls[64 * 37];   // [w][ic/2] bf16x2, stride 37 (conflict-free)
    int bid = blockIdx.x;                  // (nb*32 + d)*8 + hq
    int hq = bid & 7, d = (bid >> 3) & 31, nb = bid >> 8;
    int tid = threadIdx.x;
    int w4 = tid & 15;                     // float4 index along w
    int kp = tid >> 4;                     // 0..15

    for (int hi = 0; hi < 8; ++hi) {
        int h = hq * 8 + hi;
        float4 v0[2], v1[2];
#pragma unroll
        for (int r = 0; r < 2; ++r) {
            int p = r * 16 + kp;           // ic pair index 0..31
            const float* src = x + ((((size_t)nb * 64 + 2 * p) * 32 + d) * 64 + h) * 64 + w4 * 4;
            v0[r] = *(const float4*)(src);
            v1[r] = *(const float4*)(src + 32 * 64 * 64);   // ic+1 plane
        }
        __syncthreads();   // prior iteration's reads complete
#pragma unroll
        for (int r = 0; r < 2; ++r) {
            int p = r * 16 + kp;
            ls[(w4 * 4 + 0) * 37 + p] = pack2(v0[r].x, v1[r].x);
            ls[(w4 * 4 + 1) * 37 + p] = pack2(v0[r].y, v1[r].y);
            ls[(w4 * 4 + 2) * 37 + p] = pack2(v0[r].z, v1[r].z);
            ls[(w4 * 4 + 3) * 37 + p] = pack2(v0[r].w, v1[r].w);
        }
        __syncthreads();
        __hip_bfloat16* obase = xT + (((size_t)nb * 32 + d) * 64 + h) * 4096;
#pragma unroll
        for (int c = tid; c < 512; c += 256) {
            int ww = c >> 3, icc = c & 7;
            const unsigned int* q = ls + ww * 37 + icc * 4;
            uint4 v;
            v.x = q[0]; v.y = q[1]; v.z = q[2]; v.w = q[3];
            *(uint4*)(obase + ww * 64 + icc * 8) = v;
        }
    }
}

// ---- implicit GEMM conv -------------------------------------------------
// block: 64 oc x 256 spatial (4 h-rows x 64 w), wave w owns h-row w.
// per ky: stage sB[row 0..5][wcol][ic] (XOR-swizzled) once; per tap (9/ky):
// double-buffered A[tap] in sA (8KB x2), 2 ich K-steps from LDS, 1 barrier.
__global__ __launch_bounds__(256, 2) void conv_mfma(const __hip_bfloat16* __restrict__ xT,
                                                    const __hip_bfloat16* __restrict__ wT,
                                                    const float* __restrict__ Bp,
                                                    float* __restrict__ out) {
    __shared__ __align__(16) short sB[6 * 4096 + 128];   // 49,408 B (+kt slack)
    __shared__ __align__(16) short sA[2 * 4096];         // 16,384 B (A dbuf)

    int orig = blockIdx.x;                     // 1920 blocks, 1920 % 8 == 0
    int bid = (orig & 7) * 240 + (orig >> 3);  // bijective XCD swizzle
    int ht = bid % 16;                 // h-tile of 4 rows
    int d  = (bid / 16) % 30;
    int nb = bid / 480;
    int h0 = ht * 4;

    int tid = threadIdx.x;
    int w = tid >> 6;                  // wave id = h-row
    int lane = tid & 63;
    int quad = lane >> 4, col = lane & 15;

    f32x4 acc[4][4];
#pragma unroll
    for (int mt = 0; mt < 4; ++mt)
#pragma unroll
        for (int nt = 0; nt < 4; ++nt) acc[mt][nt] = (f32x4)(0.0f);

    // pre-swizzled per-lane source offset (shorts), shared by A and B staging:
    // LDS[row r][chunk c] = G[row r][chunk c ^ (r&7)]  (row=128B, chunk=16B)
    int srcl = ((lane >> 3) << 6) + (((lane & 7) ^ (lane >> 3)) << 3);

    const __hip_bfloat16* xb = xT + (size_t)nb * 8388608 + (size_t)d * 262144;

    // prologue: stage A[tap 0] into sA buf 0 (2 segs of 1KB per wave)
#pragma unroll
    for (int i = 0; i < 2; ++i) {
        int p = w * 2 + i;
        gl_lds16(wT + p * 512 + srcl, (char*)sA + p * 1024);
    }

    for (int ky = 0; ky < 3; ++ky) {
        // stage 48KB B slab (prev ky's reads all done before its last barrier)
#pragma unroll
        for (int i = 0; i < 12; ++i) {
            int p = w + i * 4;                 // seg: row = p>>3, j = p&7
            int hh = h0 + (p >> 3);
            if (hh > 63) hh = 63;              // clamped rows feed only discarded outputs
            gl_lds16(xb + (size_t)ky * 262144 + hh * 4096 + (p & 7) * 512 + srcl,
                     (char*)sB + p * 1024);
        }
        __syncthreads();   // slab + pending A stage landed

#pragma unroll
        for (int t = 0; t < 9; ++t) {
            // issue stage of A[g+1] into abuf[(g+1)&1]  (g = ky*9 + t)
            {
                const __hip_bfloat16* asrc = wT + (ky * 9 + t + 1) * 4096 + srcl;
                char* adst = (char*)sA + (((ky * 9 + t + 1) & 1) ? 8192 : 0);
#pragma unroll
                for (int i = 0; i < 2; ++i) {
                    int p = w * 2 + i;
                    gl_lds16(asrc + p * 512, adst + p * 1024);
                }
            }

            const int kt = t % 3, kx = t / 3;
            const short* aBase = sA + ((ky * 9 + t) & 1) * 4096;
            int wc = col + kt;
            const short* pb = sB + ((w + kx) * 64 + wc) * 64;
            int bswz = (quad * 8) ^ ((wc & 7) << 3);

#pragma unroll
            for (int ich = 0; ich < 2; ++ich) {
                bf16x8 af[4], bfr[4];
#pragma unroll
                for (int mt = 0; mt < 4; ++mt)
                    af[mt] = *(const bf16x8*)(aBase + col * 64 + mt * 1024
                                              + (((ich * 4 + quad) ^ (col & 7)) << 3));
#pragma unroll
                for (int nt = 0; nt < 4; ++nt)
                    bfr[nt] = *(const bf16x8*)(pb + ((ich * 32) ^ bswz) + nt * 1024);

                __builtin_amdgcn_s_setprio(1);
#pragma unroll
                for (int mt = 0; mt < 4; ++mt)
#pragma unroll
                    for (int nt = 0; nt < 4; ++nt)
                        acc[mt][nt] = __builtin_amdgcn_mfma_f32_16x16x32_bf16(
                            af[mt], bfr[nt], acc[mt][nt], 0, 0, 0);
                __builtin_amdgcn_s_setprio(0);
            }

            __syncthreads();   // A[g+1] landed (drains only the 2 loads above);
                               // abuf[g&1] reads done before overwrite at g+2
        }
    }

    // epilogue: D row = quad*4 + r (oc), col = n
    int hrow = h0 + w;
    if (hrow < 62) {
#pragma unroll
        for (int mt = 0; mt < 4; ++mt) {
            float bias = Bp[mt * 4 + quad];
#pragma unroll
            for (int nt = 0; nt < 4; ++nt) {
                int wp = nt * 16 + col;
                if (wp < 62) {
#pragma unroll
                    for (int r = 0; r < 4; ++r) {
                        int oc = mt * 16 + quad * 4 + r;
                        out[(((size_t)nb * 64 + oc) * 30 + d) * 3844 + hrow * 62 + wp]
                            = acc[mt][nt][r] + bias;
                    }
                }
            }
        }
    }
}

extern "C" void kernel_launch(void* const* d_in, const int* in_sizes, int n_in,
                              void* d_out, int out_size, void* d_ws, size_t ws_size,
                              hipStream_t stream) {
    const float* x = (const float*)d_in[0];
    const float* W = (const float*)d_in[1];
    const float* Bp = (const float*)d_in[2];
    float* out = (float*)d_out;

    char* ws = (char*)d_ws;
    __hip_bfloat16* wT = (__hip_bfloat16*)ws;              // 221,184 B
    __hip_bfloat16* xT = (__hip_bfloat16*)(ws + 262144);   // 67,108,864 B

    build_wT<<<(27 * 64 * 64 + 255) / 256, 256, 0, stream>>>(W, wT);
    transpose_x<<<4 * 32 * 8, 256, 0, stream>>>(x, xT);
    conv_mfma<<<4 * 30 * 16, 256, 0, stream>>>(xT, wT, Bp, out);
}